// Round 8
// baseline (90.192 us; speedup 1.0000x reference)
//
#include <hip/hip_runtime.h>
#include <math.h>

#define NC 32
#define NSTEPS 32
#define NB 8192            // composed-map intervals per theta (2^13)

// ---------------------------------------------------------------------------
// K1: per-(theta,cell) coefficients. tabs[j*64 + c] = A = e^a,
// tabs[j*64 + 32 + c] = 32*b*phi(a) (z-domain offset). Arithmetic identical
// to rounds 0-7 (absmax canary depends on it).
// ---------------------------------------------------------------------------
__global__ void trels_kernel(const float* __restrict__ theta,
                             const float* __restrict__ basis,
                             float* __restrict__ tabs,
                             int n_theta, int d) {
    int i = threadIdx.x;
    if (i >= n_theta * NC) return;
    int j = i >> 5, c = i & 31;
    float a = 0.0f, b = 0.0f;
    for (int k = 0; k < d; ++k) {
        float t = theta[j * d + k];
        a = fmaf(basis[(2 * c) * d + k],     t, a);
        b = fmaf(basis[(2 * c + 1) * d + k], t, b);
    }
    const float dT = 1.0f / (float)NSTEPS;
    a *= dT; b *= dT;
    float A = expf(a);
    float phi = (fabsf(a) < 1e-6f) ? (1.0f + 0.5f * a) : (expm1f(a) / a);
    tabs[j * 64 + c]      = A;
    tabs[j * 64 + 32 + c] = 32.0f * (b * phi);   // exact 2^5 scale
}

// ---------------------------------------------------------------------------
// K2: compose the 32-step map on NB dyadic intervals per theta.
// Interval i covers x in [i*2^-13, (i+1)*2^-13)  ->  z = 32x in
// [i*2^-8, pred((i+1)*2^-8)]. Both endpoints are tracked through the EXACT
// z-domain recurrence (same med3/cvt/fmaf as the fallback); fp32 fmaf is
// monotone in z (A>0) and floor/clamp monotone, so if cell(zlo)==cell(zhi)
// at every step then every fp32 x in the interval follows the same cell
// sequence ("pure"). For pure intervals the composed affine (S,T) is
// accumulated in fp64; impure intervals are flagged via sign(S) (S>0 always).
// ---------------------------------------------------------------------------
__global__ void __launch_bounds__(256)
compose_kernel(const float* __restrict__ tabs,
               float2* __restrict__ ST) {
    __shared__ float tb[64];
    const int j  = blockIdx.x >> 5;          // 32 blocks per theta (NB/256)
    const int i0 = (blockIdx.x & 31) * 256;
    if (threadIdx.x < 64) tb[threadIdx.x] = tabs[j * 64 + threadIdx.x];
    __syncthreads();

    const int i = i0 + threadIdx.x;
    float zlo = (float)i * 0.00390625f;                       // i*2^-8 exact
    float zhi = __uint_as_float(
        __float_as_uint((float)(i + 1) * 0.00390625f) - 1u);  // pred, exact
    double Sd = 1.0, Td = 0.0;
    bool pure = true;
#pragma unroll
    for (int s = 0; s < NSTEPS; ++s) {
        float flo = fminf(fmaxf(zlo, 0.0f), 31.5f);
        float fhi = fminf(fmaxf(zhi, 0.0f), 31.5f);
        int clo = (int)flo, chi = (int)fhi;
        pure = pure && (clo == chi);
        float Al = tb[clo],  Bl = tb[32 + clo];
        float Ah = tb[chi],  Bh = tb[32 + chi];
        Sd *= (double)Al;
        Td = fma((double)Al, Td, (double)Bl);
        zlo = fmaf(Al, zlo, Bl);
        zhi = fmaf(Ah, zhi, Bh);
    }
    float S = (float)Sd;
    // out(x) = (S*32x + T)/32 = fmaf(S, x, T/32); /32 exact in double
    ST[j * NB + i] = make_float2(pure ? S : -S, (float)(Td * (1.0 / 32.0)));
}

// ---------------------------------------------------------------------------
// K3: main pass. One theta per block; its (S,T) table staged to LDS (64 KB).
// Per point: ONE LDS b64 gather + one fma (vs 32 gathers before). Impure
// points are compacted into a per-block LDS list, flushed with a single
// global atomic per block.
// ---------------------------------------------------------------------------
constexpr int MT   = 512;          // threads per block
constexpr int MPTS = 8;
constexpr int MCHUNK = MT * MPTS;  // 4096 points per block

__global__ void __launch_bounds__(MT)
main_kernel(const float* __restrict__ points,
            const float2* __restrict__ ST,
            float* __restrict__ out,
            unsigned* __restrict__ list,
            unsigned* __restrict__ cnt,
            int n_points) {
    __shared__ float2 st[NB];                  // 64 KB
    __shared__ unsigned short ll[MCHUNK];      // 8 KB
    __shared__ unsigned lcnt, gbase;

    const int bpt = n_points / MCHUNK;
    const int j = blockIdx.x / bpt;
    const int cbase = (blockIdx.x % bpt) * MCHUNK;
    const int tid = threadIdx.x;

    {   // stage composed table (4096 float4)
        const float4* src = (const float4*)(ST + j * NB);
        float4* dst = (float4*)st;
        for (int k = tid; k < NB / 2; k += MT) dst[k] = src[k];
    }
    if (tid == 0) lcnt = 0;
    __syncthreads();

#pragma unroll
    for (int i = 0; i < MPTS; ++i) {
        int p = cbase + i * MT + tid;          // coalesced
        float x = points[p];
        float f = fminf(fmaxf(x * 8192.0f, 0.0f), 8191.5f); // exact 2^13 mul
        float2 t = st[(int)f];
        if (t.x > 0.0f) {
            out[j * n_points + p] = fmaf(t.x, x, t.y);
        } else {
            unsigned s = atomicAdd(&lcnt, 1u);
            ll[s] = (unsigned short)(i * MT + tid);
        }
    }
    __syncthreads();
    if (tid == 0 && lcnt) gbase = atomicAdd(cnt, lcnt);
    __syncthreads();
    unsigned jn = (unsigned)(j * n_points + cbase);
    for (unsigned k = tid; k < lcnt; k += MT)
        list[gbase + k] = jn + ll[k];
}

// ---------------------------------------------------------------------------
// K4: fallback — bit-exact R7 chain for listed points (expected <=12.5%).
// List is j-major (blocks append in j order) so waves are mostly
// single-theta -> table gathers stay in the cheap 2-way regime.
// ---------------------------------------------------------------------------
__global__ void __launch_bounds__(256)
fallback_kernel(const float* __restrict__ points,
                const float* __restrict__ tabs,
                float* __restrict__ out,
                const unsigned* __restrict__ list,
                const unsigned* __restrict__ cnt,
                int n_points, int n_theta) {
    __shared__ float tb[512];
    for (int k = threadIdx.x; k < n_theta * 64; k += 256) tb[k] = tabs[k];
    __syncthreads();
    unsigned n = *cnt;
    for (unsigned k = blockIdx.x * 256 + threadIdx.x; k < n;
         k += gridDim.x * 256) {
        unsigned gid = list[k];
        unsigned j = gid / (unsigned)n_points;
        unsigned p = gid - j * (unsigned)n_points;
        float z = points[p] * 32.0f;           // exact 2^5 scale
        int base = j * 64;
#pragma unroll
        for (int s = 0; s < NSTEPS; ++s) {
            float zc = fminf(fmaxf(z, 0.0f), 31.5f);
            int c = (int)zc;
            z = fmaf(tb[base + c], z, tb[base + 32 + c]);
        }
        out[gid] = z * 0.03125f;               // exact scale back
    }
}

extern "C" void kernel_launch(void* const* d_in, const int* in_sizes, int n_in,
                              void* d_out, int out_size, void* d_ws, size_t ws_size,
                              hipStream_t stream) {
    const float* points = (const float*)d_in[0];  // [1, n_points]
    const float* theta  = (const float*)d_in[1];  // [n_theta, d]
    const float* basis  = (const float*)d_in[2];  // [2*NC, d]

    int n_points = in_sizes[0];
    int d        = in_sizes[2] / (2 * NC);        // 30
    int n_theta  = in_sizes[1] / d;               // 8

    // ws layout: tabs (2 KB) | ST (512 KB) | cnt | list (8 MB)
    char* ws = (char*)d_ws;
    float*    tabs = (float*)ws;
    float2*   ST   = (float2*)(ws + 4096);
    unsigned* cnt  = (unsigned*)(ws + (1 << 20));
    unsigned* list = (unsigned*)(ws + (1 << 20) + 4096);

    hipMemsetAsync(cnt, 0, sizeof(unsigned), stream);
    trels_kernel<<<1, 256, 0, stream>>>(theta, basis, tabs, n_theta, d);
    compose_kernel<<<n_theta * (NB / 256), 256, 0, stream>>>(tabs, ST);
    main_kernel<<<n_theta * (n_points / MCHUNK), MT, 0, stream>>>(
        points, ST, (float*)d_out, list, cnt, n_points);
    fallback_kernel<<<512, 256, 0, stream>>>(
        points, tabs, (float*)d_out, list, cnt, n_points, n_theta);
}

// Round 9
// 72.409 us; speedup vs baseline: 1.2456x; 1.2456x over previous
//
#include <hip/hip_runtime.h>
#include <math.h>

#define NC 32
#define NSTEPS 32
#define NB 8192            // composed-map intervals per theta (2^13)

// ---------------------------------------------------------------------------
// Shared helper: compute this theta's chain table into LDS.
//   tb[c]      = A_c   = e^a
//   tb[32 + c] = Bz_c  = 32 * b * phi(a)     (z-domain offset, exact 2^5)
// Arithmetic identical to rounds 0-8 (absmax canary depends on it).
// Caller must __syncthreads() after.
// ---------------------------------------------------------------------------
__device__ inline void compute_tab(float* tb, const float* __restrict__ theta,
                                   const float* __restrict__ basis,
                                   int j, int d, int tid) {
    if (tid < NC) {
        const int c = tid;
        const float* __restrict__ th = theta + j * d;
        const float* __restrict__ ba = basis + (2 * c) * d;
        const float* __restrict__ bb = basis + (2 * c + 1) * d;
        float a = 0.0f, b = 0.0f;
#pragma unroll 6
        for (int k = 0; k < d; ++k) {
            float t = th[k];
            a = fmaf(ba[k], t, a);
            b = fmaf(bb[k], t, b);
        }
        const float dT = 1.0f / (float)NSTEPS;
        a *= dT;
        b *= dT;
        float A = expf(a);
        // phi(a) = (e^a - 1)/a, stable small-a branch (matches reference)
        float phi = (fabsf(a) < 1e-6f) ? (1.0f + 0.5f * a) : (expm1f(a) / a);
        tb[c]      = A;
        tb[c + NC] = 32.0f * (b * phi);
    }
}

// ---------------------------------------------------------------------------
// K1: compose the 32-step map on NB dyadic intervals per theta.
// Interval i covers x in [i*2^-13, (i+1)*2^-13) -> z = 32x in
// [i*2^-8, pred((i+1)*2^-8)]. Both endpoints run the EXACT fp32 z-domain
// recurrence; each step map is monotone in z (A>0, RN rounding monotone) and
// cell = clip(floor) is monotone, so if cell(zlo)==cell(zhi) at every step
// ("pure") every fp32 point in the interval follows the same cell sequence.
// Pure: composed affine (S, T) accumulated in fp64. Impure: flagged by -S.
// Each block recomputes its theta's 64-coeff table (cheap, kills the serial
// trels kernel + global round-trip).
// ---------------------------------------------------------------------------
__global__ void __launch_bounds__(256)
compose_kernel(const float* __restrict__ theta,
               const float* __restrict__ basis,
               float2* __restrict__ ST, int d) {
    __shared__ float tb[2 * NC];
    const int j  = blockIdx.x >> 5;          // 32 blocks per theta
    const int i0 = (blockIdx.x & 31) * 256;

    compute_tab(tb, theta, basis, j, d, threadIdx.x);
    __syncthreads();

    const int i = i0 + threadIdx.x;
    float zlo = (float)i * 0.00390625f;                       // i*2^-8 exact
    float zhi = __uint_as_float(
        __float_as_uint((float)(i + 1) * 0.00390625f) - 1u);  // pred, exact
    double Sd = 1.0, Td = 0.0;
    bool pure = true;
#pragma unroll
    for (int s = 0; s < NSTEPS; ++s) {
        float flo = fminf(fmaxf(zlo, 0.0f), 31.5f);
        float fhi = fminf(fmaxf(zhi, 0.0f), 31.5f);
        int clo = (int)flo, chi = (int)fhi;
        pure = pure && (clo == chi);
        float Al = tb[clo], Bl = tb[NC + clo];
        float Ah = tb[chi], Bh = tb[NC + chi];
        Sd *= (double)Al;
        Td = fma((double)Al, Td, (double)Bl);
        zlo = fmaf(Al, zlo, Bl);
        zhi = fmaf(Ah, zhi, Bh);
    }
    float S = (float)Sd;
    // out(x) = (S*32x + T)/32 = fmaf(S, x, T/32); /32 exact
    ST[j * NB + i] = make_float2(pure ? S : -S, (float)(Td * (1.0 / 32.0)));
}

// ---------------------------------------------------------------------------
// K2: main pass. One theta per block (512 thr, CHUNK=4096, LDS ~74 KB ->
// 2 blocks/CU). Phase 0: recompute chain table (bit-identical) + stage the
// theta's 64 KB (S,T) table from L2. Phase 1: per point ONE LDS gather +
// fma; impure offsets appended to an LDS ushort list. Phase 2 (same block):
// bit-exact 32-step chain for listed points (~12.5%); chain gathers hit a
// 64-dword table -> same-address broadcast merge (free).
// ---------------------------------------------------------------------------
constexpr int MT     = 512;
constexpr int MPTS   = 8;
constexpr int MCHUNK = MT * MPTS;          // 4096 points per block

__global__ void __launch_bounds__(MT)
main_kernel(const float* __restrict__ points,
            const float* __restrict__ theta,
            const float* __restrict__ basis,
            const float2* __restrict__ ST,
            float* __restrict__ out,
            int n_points, int d) {
    __shared__ float2 st[NB];                  // 64 KB composed table
    __shared__ unsigned short ll[MCHUNK];      // 8 KB impure list
    __shared__ float tb[2 * NC];               // 256 B chain table
    __shared__ unsigned lcnt;

    const int bpt = n_points / MCHUNK;         // 64 blocks per theta
    const int j = blockIdx.x / bpt;
    const int cbase = (blockIdx.x % bpt) * MCHUNK;
    const int tid = threadIdx.x;

    compute_tab(tb, theta, basis, j, d, tid);
    {   // stage composed table: 4096 float4 from L2-resident ST
        const float4* src = (const float4*)(ST + j * NB);
        float4* dst = (float4*)st;
#pragma unroll
        for (int k = 0; k < NB / 2 / MT; ++k)
            dst[k * MT + tid] = src[k * MT + tid];
    }
    if (tid == 0) lcnt = 0;
    __syncthreads();

    // Phase 1: pure points — one gather + one fma each.
#pragma unroll
    for (int i = 0; i < MPTS; ++i) {
        int off = i * MT + tid;
        float x = points[cbase + off];         // coalesced
        float f = fminf(fmaxf(x * 8192.0f, 0.0f), 8191.5f); // exact 2^13
        float2 t = st[(int)f];
        if (t.x > 0.0f) {
            out[j * n_points + cbase + off] = fmaf(t.x, x, t.y);
        } else {
            unsigned s = atomicAdd(&lcnt, 1u);
            ll[s] = (unsigned short)off;
        }
    }
    __syncthreads();

    // Phase 2: impure points — bit-exact 32-step chain.
    unsigned n = lcnt;
    for (unsigned k = tid; k < n; k += MT) {
        int off = ll[k];
        float z = points[cbase + off] * 32.0f; // exact 2^5 scale
#pragma unroll
        for (int s = 0; s < NSTEPS; ++s) {
            float zc = fminf(fmaxf(z, 0.0f), 31.5f);
            int c = (int)zc;
            z = fmaf(tb[c], z, tb[NC + c]);
        }
        out[j * n_points + cbase + off] = z * 0.03125f; // exact scale back
    }
}

extern "C" void kernel_launch(void* const* d_in, const int* in_sizes, int n_in,
                              void* d_out, int out_size, void* d_ws, size_t ws_size,
                              hipStream_t stream) {
    const float* points = (const float*)d_in[0];  // [1, n_points]
    const float* theta  = (const float*)d_in[1];  // [n_theta, d]
    const float* basis  = (const float*)d_in[2];  // [2*NC, d]

    int n_points = in_sizes[0];
    int d        = in_sizes[2] / (2 * NC);        // 30
    int n_theta  = in_sizes[1] / d;               // 8

    float2* ST = (float2*)d_ws;                   // n_theta*NB float2 = 512 KB

    compose_kernel<<<n_theta * (NB / 256), 256, 0, stream>>>(
        theta, basis, ST, d);
    main_kernel<<<n_theta * (n_points / MCHUNK), MT, 0, stream>>>(
        points, theta, basis, ST, (float*)d_out, n_points, d);
}